// Round 4
// baseline (221.014 us; speedup 1.0000x reference)
//
#include <hip/hip_runtime.h>

// ---------- types ----------
typedef unsigned short u16;
typedef __bf16 bf16x8 __attribute__((ext_vector_type(8)));
typedef float f32x4 __attribute__((ext_vector_type(4)));
typedef float f32x16 __attribute__((ext_vector_type(16)));
typedef u16 u16x4 __attribute__((ext_vector_type(4)));
typedef unsigned int uint;

// B=2, T=2048, DM=1024, H=16, DH=64, M = B*T = 4096
#define DM 1024
#define MROWS 4096
#define TSEQ 2048

static __device__ __forceinline__ u16 f2b(float f) {
  uint u = __builtin_bit_cast(uint, f);
  uint r = (u + 0x7fffu + ((u >> 16) & 1u)) >> 16;  // RTN-even
  return (u16)r;
}

static __device__ __forceinline__ uint pkbf(float a, float b) {
  union { __bf16 h[2]; uint u; } x;
  x.h[0] = (__bf16)a; x.h[1] = (__bf16)b;
  return x.u;
}

// ---------- f32 -> bf16 conversion (optionally scaled) ----------
__global__ __launch_bounds__(256) void cvt_kernel(const float* __restrict__ in,
                                                  u16* __restrict__ out, int n,
                                                  float scale) {
  int i = (blockIdx.x * 256 + threadIdx.x) * 4;
  if (i >= n) return;
  float4 v = *(const float4*)(in + i);
  u16x4 o;
  o.x = f2b(v.x * scale); o.y = f2b(v.y * scale);
  o.z = f2b(v.z * scale); o.w = f2b(v.w * scale);
  *(u16x4*)(out + i) = o;
}

// ---------- GEMM core: C[128x128] = A[128xK] * W[128xK]^T, K=1024 ----------
#define SWZ(o) ((o) ^ ((((o) >> 7) & 3) << 4))

static __device__ __forceinline__ void gemm_tile(const u16* __restrict__ A,
                                                 const u16* __restrict__ W,
                                                 int row0, int col0,
                                                 char* ldsA, char* ldsB,
                                                 f32x4 (&acc)[4][4]) {
  const int tid = threadIdx.x;
  const int lane = tid & 63, wid = tid >> 6;
  const int wr = wid >> 1, wc = wid & 1;
  const int lg = lane >> 4, lr = lane & 15;

  f32x4 z = {0.f, 0.f, 0.f, 0.f};
#pragma unroll
  for (int m = 0; m < 4; ++m)
#pragma unroll
    for (int n = 0; n < 4; ++n) acc[m][n] = z;

  for (int k0 = 0; k0 < DM; k0 += 32) {
#pragma unroll
    for (int c = 0; c < 2; ++c) {
      int lin = (c * 256 + tid) * 16;
      int p = SWZ(lin);
      int rowl = p >> 6;
      int cb = p & 63;
      const char* ga = (const char*)(A + (size_t)(row0 + rowl) * DM + k0) + cb;
      __builtin_amdgcn_global_load_lds(
          (const __attribute__((address_space(1))) void*)ga,
          (__attribute__((address_space(3))) void*)(ldsA + lin), 16, 0, 0);
      const char* gb = (const char*)(W + (size_t)(col0 + rowl) * DM + k0) + cb;
      __builtin_amdgcn_global_load_lds(
          (const __attribute__((address_space(1))) void*)gb,
          (__attribute__((address_space(3))) void*)(ldsB + lin), 16, 0, 0);
    }
    __syncthreads();

    bf16x8 av[4], bv[4];
#pragma unroll
    for (int m = 0; m < 4; ++m) {
      int bo = (wr * 64 + m * 16 + lr) * 64 + lg * 16;
      av[m] = *(const bf16x8*)(ldsA + SWZ(bo));
    }
#pragma unroll
    for (int n = 0; n < 4; ++n) {
      int bo = (wc * 64 + n * 16 + lr) * 64 + lg * 16;
      bv[n] = *(const bf16x8*)(ldsB + SWZ(bo));
    }
#pragma unroll
    for (int m = 0; m < 4; ++m)
#pragma unroll
      for (int n = 0; n < 4; ++n)
        acc[m][n] = __builtin_amdgcn_mfma_f32_16x16x32_bf16(av[m], bv[n], acc[m][n], 0, 0, 0);
    __syncthreads();
  }
}

// ---------- fused QKV projection ----------
__global__ __launch_bounds__(256) void qkv_gemm(
    const u16* __restrict__ xb, const u16* __restrict__ Wqb,
    const u16* __restrict__ Wkb, const u16* __restrict__ Wvb,
    const float* __restrict__ bq, const float* __restrict__ bk,
    const float* __restrict__ bv, u16* __restrict__ Qb, u16* __restrict__ Kb,
    u16* __restrict__ VT) {
  __shared__ char lds[16384];
  const int seg = blockIdx.x >> 3, nt = blockIdx.x & 7;
  const int row0 = blockIdx.y * 128, col0 = nt * 128;
  const u16* W = (seg == 0) ? Wqb : (seg == 1) ? Wkb : Wvb;
  const float* bias = (seg == 0) ? bq : (seg == 1) ? bk : bv;
  // Q carries 1/sqrt(64) * log2(e) so attention works in exp2 domain
  const float bscale = (seg == 0) ? 0.18033688011112042f : 1.0f;

  f32x4 acc[4][4];
  gemm_tile(xb, W, row0, col0, lds, lds + 8192, acc);

  const int tid = threadIdx.x;
  const int lane = tid & 63, wid = tid >> 6;
  const int wr = wid >> 1, wc = wid & 1;
  const int lg = lane >> 4, lr = lane & 15;

  if (seg < 2) {
    u16* out = (seg == 0) ? Qb : Kb;
#pragma unroll
    for (int m = 0; m < 4; ++m)
#pragma unroll
      for (int n = 0; n < 4; ++n) {
        int col = col0 + wc * 64 + n * 16 + lr;
        float b = bias[col] * bscale;
#pragma unroll
        for (int r = 0; r < 4; ++r) {
          int row = row0 + wr * 64 + m * 16 + lg * 4 + r;
          out[(size_t)row * DM + col] = f2b(acc[m][n][r] + b);
        }
      }
  } else {
    // write transposed + kv-bit-swap (bits 2<->3 of t) so attn's PV
    // A-fragment (permuted kv order) is one contiguous b128 load.
#pragma unroll
    for (int m = 0; m < 4; ++m)
#pragma unroll
      for (int n = 0; n < 4; ++n) {
        int col = col0 + wc * 64 + n * 16 + lr;
        float b = bias[col];
        int t = row0 + wr * 64 + m * 16 + lg * 4;
        int bi = t >> 11, tt = t & 2047;
        int tt2 = (tt & ~12) | ((tt & 4) << 1) | ((tt & 8) >> 1);
        int hh = col >> 6, dd = col & 63;
        u16x4 pk;
        pk.x = f2b(acc[m][n][0] + b);
        pk.y = f2b(acc[m][n][1] + b);
        pk.z = f2b(acc[m][n][2] + b);
        pk.w = f2b(acc[m][n][3] + b);
        *(u16x4*)(VT + ((size_t)((bi * 16 + hh) * 64 + dd)) * 2048 + tt2) = pk;
      }
  }
}

// ---------- flash attention (causal), kv-split x2 + in-LDS merge ----------
// Block = one 64-row q-tile: 4 waves = {2 row-halves} x {2 kv-splits}.
// Grid 1024 -> 4 blocks/CU -> 16 waves/CU (50% occ). LPT: longest q-tiles
// first per XCD; 4 heads per XCD keeps K/V in its L2 (~3MB < 4MB).
// Per wave: S^T = mfma(K,Q), lane owns q-row; O^T = mfma(V^T,P^T).
// Split-1 waves write unnormalized (O,m,l) to LDS; split-0 merge + store.
__global__ __launch_bounds__(256, 4) void attn_kernel(const u16* __restrict__ Q,
                                                      const u16* __restrict__ K,
                                                      const u16* __restrict__ VT,
                                                      u16* __restrict__ Aout) {
  __shared__ float mrg[2][64][32];  // per row-half merge buf, XOR-chunk swizzle
  __shared__ float mml[2][32][2];   // (m,l) per row
  const int tid = threadIdx.x, lane = tid & 63, wid = tid >> 6;
  const int hi = lane >> 5, ln = lane & 31;
  const int id = blockIdx.x + (blockIdx.y << 5);
  const int xcd = id & 7, idx = id >> 3;
  const int bh = xcd * 4 + (idx & 3);   // 4 heads per XCD
  const int qt = 31 - (idx >> 2);       // LPT: big q-tiles first
  const int b = bh >> 4, h = bh & 15;
  const int q0 = qt * 64 + (wid & 1) * 32;
  const int spl = wid >> 1;             // kv split id
  const int ntile = (q0 >> 5) + 1;
  const int half = (ntile + 1) >> 1;
  const int tbeg = spl ? half : 0;
  const int tend = spl ? ntile : half;

  const u16* Qb = Q + (size_t)b * TSEQ * DM + h * 64;
  const u16* Kb = K + (size_t)b * TSEQ * DM + h * 64;
  const u16* Vb = VT + (size_t)bh * 64 * TSEQ;

  bf16x8 qf[4];
#pragma unroll
  for (int c = 0; c < 4; ++c)
    qf[c] = *(const bf16x8*)(Qb + (size_t)(q0 + ln) * DM + c * 16 + hi * 8);

  f32x16 Oa, Ob;
#pragma unroll
  for (int r = 0; r < 16; ++r) { Oa[r] = 0.f; Ob[r] = 0.f; }
  float m = -1e30f, l = 0.f;

  auto loadK = [&](int k0, bf16x8 (&kf)[4]) {
#pragma unroll
    for (int c = 0; c < 4; ++c)
      kf[c] = *(const bf16x8*)(Kb + (size_t)(k0 + ln) * DM + c * 16 + hi * 8);
  };
  auto loadV = [&](int k0, bf16x8 (&vf)[4]) {
#pragma unroll
    for (int c = 0; c < 2; ++c)
#pragma unroll
      for (int hh = 0; hh < 2; ++hh)
        vf[2 * c + hh] = *(const bf16x8*)(Vb + (size_t)(hh * 32 + ln) * TSEQ +
                                          k0 + c * 16 + hi * 8);
  };
  auto tile = [&](const bf16x8 (&kf)[4], const bf16x8 (&vf)[4], int k0, bool diag) {
    f32x16 S;
#pragma unroll
    for (int r = 0; r < 16; ++r) S[r] = 0.f;
    __builtin_amdgcn_s_setprio(1);
#pragma unroll
    for (int c = 0; c < 4; ++c)
      S = __builtin_amdgcn_mfma_f32_32x32x16_bf16(kf[c], qf[c], S, 0, 0, 0);
    __builtin_amdgcn_s_setprio(0);
    if (diag) {
      const int q = q0 + ln;
#pragma unroll
      for (int r = 0; r < 16; ++r) {
        int kv = k0 + (r & 3) + 8 * (r >> 2) + 4 * hi;
        if (kv > q) S[r] = -1e30f;
      }
    }
    float m0 = fmaxf(fmaxf(S[0], S[1]), fmaxf(S[2], S[3]));
    float m1 = fmaxf(fmaxf(S[4], S[5]), fmaxf(S[6], S[7]));
    float m2 = fmaxf(fmaxf(S[8], S[9]), fmaxf(S[10], S[11]));
    float m3 = fmaxf(fmaxf(S[12], S[13]), fmaxf(S[14], S[15]));
    float mx = fmaxf(fmaxf(m0, m1), fmaxf(m2, m3));
    mx = fmaxf(mx, __shfl_xor(mx, 32));
    if (!__all(mx - m <= 8.f)) {  // defer-max (T13), exp2 domain
      float nm = fmaxf(m, mx);
      float sf = __builtin_amdgcn_exp2f(m - nm);
      m = nm; l *= sf;
#pragma unroll
      for (int r = 0; r < 16; ++r) { Oa[r] *= sf; Ob[r] *= sf; }
    }
    float p[16];
#pragma unroll
    for (int r = 0; r < 16; ++r) p[r] = __builtin_amdgcn_exp2f(S[r] - m);
    float ts = ((p[0] + p[1]) + (p[2] + p[3])) + ((p[4] + p[5]) + (p[6] + p[7]));
    ts += ((p[8] + p[9]) + (p[10] + p[11])) + ((p[12] + p[13]) + (p[14] + p[15]));
    ts += __shfl_xor(ts, 32);
    l += ts;
    uint pw[8];
#pragma unroll
    for (int i = 0; i < 8; ++i) pw[i] = pkbf(p[2 * i], p[2 * i + 1]);
    __builtin_amdgcn_s_setprio(1);
#pragma unroll
    for (int c = 0; c < 2; ++c) {
      union { uint w[4]; bf16x8 v; } pf;
      pf.w[0] = pw[4 * c + 0]; pf.w[1] = pw[4 * c + 1];
      pf.w[2] = pw[4 * c + 2]; pf.w[3] = pw[4 * c + 3];
      Oa = __builtin_amdgcn_mfma_f32_32x32x16_bf16(vf[2 * c + 0], pf.v, Oa, 0, 0, 0);
      Ob = __builtin_amdgcn_mfma_f32_32x32x16_bf16(vf[2 * c + 1], pf.v, Ob, 0, 0, 0);
    }
    __builtin_amdgcn_s_setprio(0);
  };

  bf16x8 kA[4], vA[4], kB[4], vB[4];
  if (tbeg < tend) { loadK(tbeg * 32, kA); loadV(tbeg * 32, vA); }
  int kt = tbeg;
  for (; kt + 2 <= tend; kt += 2) {
    loadK((kt + 1) * 32, kB); loadV((kt + 1) * 32, vB);
    tile(kA, vA, kt * 32, kt == ntile - 1);
    if (kt + 2 < tend) { loadK((kt + 2) * 32, kA); loadV((kt + 2) * 32, vA); }
    tile(kB, vB, (kt + 1) * 32, kt + 1 == ntile - 1);
  }
  if (kt < tend) tile(kA, vA, kt * 32, kt == ntile - 1);

  // ---- kv-split merge via LDS ----
  union uo { f32x16 v; f32x4 q[4]; };
  const int pi = wid & 1;
  char* moc = (char*)&mrg[pi][0][0];
  const int sw8 = lane & 7;
  if (spl) {
    uo ua, ub; ua.v = Oa; ub.v = Ob;
#pragma unroll
    for (int c = 0; c < 4; ++c) {
      *(f32x4*)(moc + lane * 128 + ((c ^ sw8) * 16)) = ua.q[c];
      *(f32x4*)(moc + lane * 128 + (((c + 4) ^ sw8) * 16)) = ub.q[c];
    }
    if (hi == 0) { mml[pi][ln][0] = m; mml[pi][ln][1] = l; }
  }
  __syncthreads();
  if (spl) return;

  f32x4 rb[8];
#pragma unroll
  for (int c = 0; c < 8; ++c)
    rb[c] = *(const f32x4*)(moc + lane * 128 + ((c ^ sw8) * 16));
  float mB = mml[pi][ln][0], lB = mml[pi][ln][1];
  float M = fmaxf(m, mB);
  float eA = __builtin_amdgcn_exp2f(m - M);
  float eB = __builtin_amdgcn_exp2f(mB - M);
  float inv = 1.f / (l * eA + lB * eB);
  eA *= inv; eB *= inv;
  uo ua, ub; ua.v = Oa; ub.v = Ob;
#pragma unroll
  for (int c = 0; c < 4; ++c) {
    ua.q[c] = ua.q[c] * eA + rb[c] * eB;
    ub.q[c] = ub.q[c] * eA + rb[c + 4] * eB;
  }
  Oa = ua.v; Ob = ub.v;

  // epilogue: transpose O^T via LDS (reuse merge region), coalesced store
  char* Tc = moc;
#pragma unroll
  for (int i = 0; i < 8; ++i) {
    int d0 = (2 * i & 3) + 8 * ((2 * i) >> 2) + 4 * hi;
    uint wA = pkbf(Oa[2 * i], Oa[2 * i + 1]);
    *(uint*)(Tc + (ln * 128 + ((d0 * 2) ^ ((ln & 7) << 4)))) = wA;
    uint wB = pkbf(Ob[2 * i], Ob[2 * i + 1]);
    *(uint*)(Tc + (ln * 128 + (((d0 + 32) * 2) ^ ((ln & 7) << 4)))) = wB;
  }
  __threadfence_block();
  u16* Ap = Aout + (size_t)b * TSEQ * DM + h * 64 + (size_t)(q0 + ln) * DM;
#pragma unroll
  for (int j = 0; j < 4; ++j) {
    int oct = hi * 4 + j;
    bf16x8 v = *(const bf16x8*)(Tc + (ln * 128 + ((oct * 16) ^ ((ln & 7) << 4))));
    *(bf16x8*)(Ap + oct * 8) = v;
  }
}

// ---------- output projection: out = attn @ Wo^T + bo (f32 out) ----------
__global__ __launch_bounds__(256) void out_gemm(const u16* __restrict__ attn,
                                                const u16* __restrict__ Wob,
                                                const float* __restrict__ bo,
                                                float* __restrict__ out) {
  __shared__ char lds[16384];
  const int row0 = blockIdx.y * 128, col0 = blockIdx.x * 128;
  f32x4 acc[4][4];
  gemm_tile(attn, Wob, row0, col0, lds, lds + 8192, acc);

  const int tid = threadIdx.x;
  const int lane = tid & 63, wid = tid >> 6;
  const int wr = wid >> 1, wc = wid & 1;
  const int lg = lane >> 4, lr = lane & 15;
#pragma unroll
  for (int m = 0; m < 4; ++m)
#pragma unroll
    for (int n = 0; n < 4; ++n) {
      int col = col0 + wc * 64 + n * 16 + lr;
      float b = bo[col];
#pragma unroll
      for (int r = 0; r < 4; ++r) {
        int row = row0 + wr * 64 + m * 16 + lg * 4 + r;
        out[(size_t)row * DM + col] = acc[m][n][r] + b;
      }
    }
}

extern "C" void kernel_launch(void* const* d_in, const int* in_sizes, int n_in,
                              void* d_out, int out_size, void* d_ws, size_t ws_size,
                              hipStream_t stream) {
  const float* x = (const float*)d_in[0];
  const float* Wq = (const float*)d_in[1];
  const float* bq = (const float*)d_in[2];
  const float* Wk = (const float*)d_in[3];
  const float* bk = (const float*)d_in[4];
  const float* Wv = (const float*)d_in[5];
  const float* bv = (const float*)d_in[6];
  const float* Wo = (const float*)d_in[7];
  const float* bo = (const float*)d_in[8];

  char* ws = (char*)d_ws;
  const size_t MB = 1024 * 1024;
  u16* xb = (u16*)(ws);             // 8 MB (x bf16; reused as attn out later)
  u16* Wqb = (u16*)(ws + 8 * MB);   // 2 MB
  u16* Wkb = (u16*)(ws + 10 * MB);  // 2 MB
  u16* Wvb = (u16*)(ws + 12 * MB);  // 2 MB
  u16* Wob = (u16*)(ws + 14 * MB);  // 2 MB
  u16* Qb = (u16*)(ws + 16 * MB);   // 8 MB
  u16* Kb = (u16*)(ws + 24 * MB);   // 8 MB
  u16* VT = (u16*)(ws + 32 * MB);   // 8 MB   (total 40 MB)
  u16* attnb = xb;                  // alias: xb dead after qkv_gemm

  cvt_kernel<<<4096, 256, 0, stream>>>(x, xb, MROWS * DM, 1.0f);
  // Wq carries 1/sqrt(Dh) * log2(e)
  cvt_kernel<<<1024, 256, 0, stream>>>(Wq, Wqb, DM * DM, 0.18033688011112042f);
  cvt_kernel<<<1024, 256, 0, stream>>>(Wk, Wkb, DM * DM, 1.0f);
  cvt_kernel<<<1024, 256, 0, stream>>>(Wv, Wvb, DM * DM, 1.0f);
  cvt_kernel<<<1024, 256, 0, stream>>>(Wo, Wob, DM * DM, 1.0f);

  qkv_gemm<<<dim3(24, 32), 256, 0, stream>>>(xb, Wqb, Wkb, Wvb, bq, bk, bv, Qb, Kb, VT);
  attn_kernel<<<dim3(32, 32), 256, 0, stream>>>(Qb, Kb, VT, attnb);
  out_gemm<<<dim3(8, 32), 256, 0, stream>>>(attnb, Wob, bo, (float*)d_out);
}

// Round 5
// 159.764 us; speedup vs baseline: 1.3834x; 1.3834x over previous
//
#include <hip/hip_runtime.h>

// ---------- types ----------
typedef unsigned short u16;
typedef __bf16 bf16x8 __attribute__((ext_vector_type(8)));
typedef float f32x4 __attribute__((ext_vector_type(4)));
typedef float f32x16 __attribute__((ext_vector_type(16)));
typedef u16 u16x4 __attribute__((ext_vector_type(4)));
typedef unsigned int uint;

// B=2, T=2048, DM=1024, H=16, DH=64, M = B*T = 4096
#define DM 1024
#define MROWS 4096
#define TSEQ 2048

static __device__ __forceinline__ u16 f2b(float f) {
  uint u = __builtin_bit_cast(uint, f);
  uint r = (u + 0x7fffu + ((u >> 16) & 1u)) >> 16;  // RTN-even
  return (u16)r;
}

static __device__ __forceinline__ uint pkbf(float a, float b) {
  union { __bf16 h[2]; uint u; } x;
  x.h[0] = (__bf16)a; x.h[1] = (__bf16)b;
  return x.u;
}

// ---------- f32 -> bf16 conversion (optionally scaled) ----------
__global__ __launch_bounds__(256) void cvt_kernel(const float* __restrict__ in,
                                                  u16* __restrict__ out, int n,
                                                  float scale) {
  int i = (blockIdx.x * 256 + threadIdx.x) * 4;
  if (i >= n) return;
  float4 v = *(const float4*)(in + i);
  u16x4 o;
  o.x = f2b(v.x * scale); o.y = f2b(v.y * scale);
  o.z = f2b(v.z * scale); o.w = f2b(v.w * scale);
  *(u16x4*)(out + i) = o;
}

// batched 4-weight conversion (one launch instead of four)
__global__ __launch_bounds__(256) void cvt4_kernel(
    const float* __restrict__ w0, const float* __restrict__ w1,
    const float* __restrict__ w2, const float* __restrict__ w3,
    u16* __restrict__ o0, u16* __restrict__ o1, u16* __restrict__ o2,
    u16* __restrict__ o3, float s0) {
  const int sel = blockIdx.y;
  const float* in = (sel == 0) ? w0 : (sel == 1) ? w1 : (sel == 2) ? w2 : w3;
  u16* out = (sel == 0) ? o0 : (sel == 1) ? o1 : (sel == 2) ? o2 : o3;
  const float scale = (sel == 0) ? s0 : 1.0f;
  int i = (blockIdx.x * 256 + threadIdx.x) * 4;
  float4 v = *(const float4*)(in + i);
  u16x4 o;
  o.x = f2b(v.x * scale); o.y = f2b(v.y * scale);
  o.z = f2b(v.z * scale); o.w = f2b(v.w * scale);
  *(u16x4*)(out + i) = o;
}

// ---------- GEMM core: C[128x128] = A[128xK] * W[128xK]^T, K=1024 ----------
#define SWZ(o) ((o) ^ ((((o) >> 7) & 3) << 4))

static __device__ __forceinline__ void gemm_tile(const u16* __restrict__ A,
                                                 const u16* __restrict__ W,
                                                 int row0, int col0,
                                                 char* ldsA, char* ldsB,
                                                 f32x4 (&acc)[4][4]) {
  const int tid = threadIdx.x;
  const int lane = tid & 63, wid = tid >> 6;
  const int wr = wid >> 1, wc = wid & 1;
  const int lg = lane >> 4, lr = lane & 15;

  f32x4 z = {0.f, 0.f, 0.f, 0.f};
#pragma unroll
  for (int m = 0; m < 4; ++m)
#pragma unroll
    for (int n = 0; n < 4; ++n) acc[m][n] = z;

  for (int k0 = 0; k0 < DM; k0 += 32) {
#pragma unroll
    for (int c = 0; c < 2; ++c) {
      int lin = (c * 256 + tid) * 16;
      int p = SWZ(lin);
      int rowl = p >> 6;
      int cb = p & 63;
      const char* ga = (const char*)(A + (size_t)(row0 + rowl) * DM + k0) + cb;
      __builtin_amdgcn_global_load_lds(
          (const __attribute__((address_space(1))) void*)ga,
          (__attribute__((address_space(3))) void*)(ldsA + lin), 16, 0, 0);
      const char* gb = (const char*)(W + (size_t)(col0 + rowl) * DM + k0) + cb;
      __builtin_amdgcn_global_load_lds(
          (const __attribute__((address_space(1))) void*)gb,
          (__attribute__((address_space(3))) void*)(ldsB + lin), 16, 0, 0);
    }
    __syncthreads();

    bf16x8 av[4], bv[4];
#pragma unroll
    for (int m = 0; m < 4; ++m) {
      int bo = (wr * 64 + m * 16 + lr) * 64 + lg * 16;
      av[m] = *(const bf16x8*)(ldsA + SWZ(bo));
    }
#pragma unroll
    for (int n = 0; n < 4; ++n) {
      int bo = (wc * 64 + n * 16 + lr) * 64 + lg * 16;
      bv[n] = *(const bf16x8*)(ldsB + SWZ(bo));
    }
#pragma unroll
    for (int m = 0; m < 4; ++m)
#pragma unroll
      for (int n = 0; n < 4; ++n)
        acc[m][n] = __builtin_amdgcn_mfma_f32_16x16x32_bf16(av[m], bv[n], acc[m][n], 0, 0, 0);
    __syncthreads();
  }
}

// ---------- fused QKV projection ----------
__global__ __launch_bounds__(256) void qkv_gemm(
    const u16* __restrict__ xb, const u16* __restrict__ Wqb,
    const u16* __restrict__ Wkb, const u16* __restrict__ Wvb,
    const float* __restrict__ bq, const float* __restrict__ bk,
    const float* __restrict__ bv, u16* __restrict__ Qb, u16* __restrict__ Kb,
    u16* __restrict__ VT) {
  __shared__ char lds[16384];
  const int seg = blockIdx.x >> 3, nt = blockIdx.x & 7;
  const int row0 = blockIdx.y * 128, col0 = nt * 128;
  const u16* W = (seg == 0) ? Wqb : (seg == 1) ? Wkb : Wvb;
  const float* bias = (seg == 0) ? bq : (seg == 1) ? bk : bv;
  // Q carries 1/sqrt(64) * log2(e) so attention works in exp2 domain
  const float bscale = (seg == 0) ? 0.18033688011112042f : 1.0f;

  f32x4 acc[4][4];
  gemm_tile(xb, W, row0, col0, lds, lds + 8192, acc);

  const int tid = threadIdx.x;
  const int lane = tid & 63, wid = tid >> 6;
  const int wr = wid >> 1, wc = wid & 1;
  const int lg = lane >> 4, lr = lane & 15;

  if (seg < 2) {
    u16* out = (seg == 0) ? Qb : Kb;
#pragma unroll
    for (int m = 0; m < 4; ++m)
#pragma unroll
      for (int n = 0; n < 4; ++n) {
        int col = col0 + wc * 64 + n * 16 + lr;
        float b = bias[col] * bscale;
#pragma unroll
        for (int r = 0; r < 4; ++r) {
          int row = row0 + wr * 64 + m * 16 + lg * 4 + r;
          out[(size_t)row * DM + col] = f2b(acc[m][n][r] + b);
        }
      }
  } else {
    // write transposed + kv-bit-swap (bits 2<->3 of t) so attn's PV
    // A-fragment (permuted kv order) is one contiguous b128 load.
#pragma unroll
    for (int m = 0; m < 4; ++m)
#pragma unroll
      for (int n = 0; n < 4; ++n) {
        int col = col0 + wc * 64 + n * 16 + lr;
        float b = bias[col];
        int t = row0 + wr * 64 + m * 16 + lg * 4;
        int bi = t >> 11, tt = t & 2047;
        int tt2 = (tt & ~12) | ((tt & 4) << 1) | ((tt & 8) >> 1);
        int hh = col >> 6, dd = col & 63;
        u16x4 pk;
        pk.x = f2b(acc[m][n][0] + b);
        pk.y = f2b(acc[m][n][1] + b);
        pk.z = f2b(acc[m][n][2] + b);
        pk.w = f2b(acc[m][n][3] + b);
        *(u16x4*)(VT + ((size_t)((bi * 16 + hh) * 64 + dd)) * 2048 + tt2) = pk;
      }
  }
}

// ---------- flash attention (causal), kv-split x2 + in-LDS merge ----------
// Block = one 64-row q-tile: 4 waves = {2 row-halves} x {2 kv-splits}.
// Grid 1024 -> target 4 blocks/CU = 16 waves/CU. Register-budget discipline
// (round-4 lesson: double-buffer spilled at 128-reg cap): single K buffer
// reloaded right after QK consumes it (next-K in flight under softmax+PV),
// V issued at tile top (consumed ~250cyc later) -> latency hidden, no spill.
__global__ __launch_bounds__(256, 4) void attn_kernel(const u16* __restrict__ Q,
                                                      const u16* __restrict__ K,
                                                      const u16* __restrict__ VT,
                                                      u16* __restrict__ Aout) {
  __shared__ float mrg[2][64][32];  // per row-half merge buf, XOR-chunk swizzle
  __shared__ float mml[2][32][2];   // (m,l) per row
  const int tid = threadIdx.x, lane = tid & 63, wid = tid >> 6;
  const int hi = lane >> 5, ln = lane & 31;
  const int id = blockIdx.x + (blockIdx.y << 5);
  const int xcd = id & 7, idx = id >> 3;
  const int bh = xcd * 4 + (idx & 3);   // 4 heads per XCD
  const int qt = 31 - (idx >> 2);       // LPT: big q-tiles first
  const int b = bh >> 4, h = bh & 15;
  const int q0 = qt * 64 + (wid & 1) * 32;
  const int spl = wid >> 1;             // kv split id
  const int ntile = (q0 >> 5) + 1;
  const int half = (ntile + 1) >> 1;
  const int tbeg = spl ? half : 0;
  const int tend = spl ? ntile : half;

  const u16* Qb = Q + (size_t)b * TSEQ * DM + h * 64;
  const u16* Kb = K + (size_t)b * TSEQ * DM + h * 64;
  const u16* Vb = VT + (size_t)bh * 64 * TSEQ;

  bf16x8 qf[4];
#pragma unroll
  for (int c = 0; c < 4; ++c)
    qf[c] = *(const bf16x8*)(Qb + (size_t)(q0 + ln) * DM + c * 16 + hi * 8);

  f32x16 Oa, Ob;
#pragma unroll
  for (int r = 0; r < 16; ++r) { Oa[r] = 0.f; Ob[r] = 0.f; }
  float m = -1e30f, l = 0.f;

  bf16x8 kf[4], vf[4];
  auto loadK = [&](int k0) {
#pragma unroll
    for (int c = 0; c < 4; ++c)
      kf[c] = *(const bf16x8*)(Kb + (size_t)(k0 + ln) * DM + c * 16 + hi * 8);
  };
  auto loadV = [&](int k0) {
#pragma unroll
    for (int c = 0; c < 2; ++c)
#pragma unroll
      for (int hh = 0; hh < 2; ++hh)
        vf[2 * c + hh] = *(const bf16x8*)(Vb + (size_t)(hh * 32 + ln) * TSEQ +
                                          k0 + c * 16 + hi * 8);
  };

  if (tbeg < tend) loadK(tbeg * 32);
  for (int kt = tbeg; kt < tend; ++kt) {
    const int k0 = kt * 32;
    const bool diag = (kt == ntile - 1);
    loadV(k0);  // issued now, consumed after softmax (~250 cyc) -> hidden
    f32x16 S;
#pragma unroll
    for (int r = 0; r < 16; ++r) S[r] = 0.f;
    __builtin_amdgcn_s_setprio(1);
#pragma unroll
    for (int c = 0; c < 4; ++c)
      S = __builtin_amdgcn_mfma_f32_32x32x16_bf16(kf[c], qf[c], S, 0, 0, 0);
    __builtin_amdgcn_s_setprio(0);
    if (kt + 1 < tend) loadK(k0 + 32);  // next K in flight under softmax+PV
    if (diag) {
      const int q = q0 + ln;
#pragma unroll
      for (int r = 0; r < 16; ++r) {
        int kv = k0 + (r & 3) + 8 * (r >> 2) + 4 * hi;
        if (kv > q) S[r] = -1e30f;
      }
    }
    float m0 = fmaxf(fmaxf(S[0], S[1]), fmaxf(S[2], S[3]));
    float m1 = fmaxf(fmaxf(S[4], S[5]), fmaxf(S[6], S[7]));
    float m2 = fmaxf(fmaxf(S[8], S[9]), fmaxf(S[10], S[11]));
    float m3 = fmaxf(fmaxf(S[12], S[13]), fmaxf(S[14], S[15]));
    float mx = fmaxf(fmaxf(m0, m1), fmaxf(m2, m3));
    mx = fmaxf(mx, __shfl_xor(mx, 32));
    if (!__all(mx - m <= 8.f)) {  // defer-max (T13), exp2 domain
      float nm = fmaxf(m, mx);
      float sf = __builtin_amdgcn_exp2f(m - nm);
      m = nm; l *= sf;
#pragma unroll
      for (int r = 0; r < 16; ++r) { Oa[r] *= sf; Ob[r] *= sf; }
    }
#pragma unroll
    for (int r = 0; r < 16; ++r) S[r] = __builtin_amdgcn_exp2f(S[r] - m);
    float ts = ((S[0] + S[1]) + (S[2] + S[3])) + ((S[4] + S[5]) + (S[6] + S[7]));
    ts += ((S[8] + S[9]) + (S[10] + S[11])) + ((S[12] + S[13]) + (S[14] + S[15]));
    ts += __shfl_xor(ts, 32);
    l += ts;
    uint pw[8];
#pragma unroll
    for (int i = 0; i < 8; ++i) pw[i] = pkbf(S[2 * i], S[2 * i + 1]);
    __builtin_amdgcn_s_setprio(1);
#pragma unroll
    for (int c = 0; c < 2; ++c) {
      union { uint w[4]; bf16x8 v; } pf;
      pf.w[0] = pw[4 * c + 0]; pf.w[1] = pw[4 * c + 1];
      pf.w[2] = pw[4 * c + 2]; pf.w[3] = pw[4 * c + 3];
      Oa = __builtin_amdgcn_mfma_f32_32x32x16_bf16(vf[2 * c + 0], pf.v, Oa, 0, 0, 0);
      Ob = __builtin_amdgcn_mfma_f32_32x32x16_bf16(vf[2 * c + 1], pf.v, Ob, 0, 0, 0);
    }
    __builtin_amdgcn_s_setprio(0);
  }

  // ---- kv-split merge via LDS ----
  union uo { f32x16 v; f32x4 q[4]; };
  const int pi = wid & 1;
  char* moc = (char*)&mrg[pi][0][0];
  const int sw8 = lane & 7;
  if (spl) {
    uo ua, ub; ua.v = Oa; ub.v = Ob;
#pragma unroll
    for (int c = 0; c < 4; ++c) {
      *(f32x4*)(moc + lane * 128 + ((c ^ sw8) * 16)) = ua.q[c];
      *(f32x4*)(moc + lane * 128 + (((c + 4) ^ sw8) * 16)) = ub.q[c];
    }
    if (hi == 0) { mml[pi][ln][0] = m; mml[pi][ln][1] = l; }
  }
  __syncthreads();
  if (spl) return;

  f32x4 rb[8];
#pragma unroll
  for (int c = 0; c < 8; ++c)
    rb[c] = *(const f32x4*)(moc + lane * 128 + ((c ^ sw8) * 16));
  float mB = mml[pi][ln][0], lB = mml[pi][ln][1];
  float M = fmaxf(m, mB);
  float eA = __builtin_amdgcn_exp2f(m - M);
  float eB = __builtin_amdgcn_exp2f(mB - M);
  float inv = 1.f / (l * eA + lB * eB);
  eA *= inv; eB *= inv;
  uo ua, ub; ua.v = Oa; ub.v = Ob;
#pragma unroll
  for (int c = 0; c < 4; ++c) {
    ua.q[c] = ua.q[c] * eA + rb[c] * eB;
    ub.q[c] = ub.q[c] * eA + rb[c + 4] * eB;
  }
  Oa = ua.v; Ob = ub.v;

  // epilogue: transpose O^T via LDS (reuse merge region), coalesced store
  char* Tc = moc;
#pragma unroll
  for (int i = 0; i < 8; ++i) {
    int d0 = (2 * i & 3) + 8 * ((2 * i) >> 2) + 4 * hi;
    uint wA = pkbf(Oa[2 * i], Oa[2 * i + 1]);
    *(uint*)(Tc + (ln * 128 + ((d0 * 2) ^ ((ln & 7) << 4)))) = wA;
    uint wB = pkbf(Ob[2 * i], Ob[2 * i + 1]);
    *(uint*)(Tc + (ln * 128 + (((d0 + 32) * 2) ^ ((ln & 7) << 4)))) = wB;
  }
  __threadfence_block();
  u16* Ap = Aout + (size_t)b * TSEQ * DM + h * 64 + (size_t)(q0 + ln) * DM;
#pragma unroll
  for (int j = 0; j < 4; ++j) {
    int oct = hi * 4 + j;
    bf16x8 v = *(const bf16x8*)(Tc + (ln * 128 + ((oct * 16) ^ ((ln & 7) << 4))));
    *(bf16x8*)(Ap + oct * 8) = v;
  }
}

// ---------- output projection: out = attn @ Wo^T + bo (f32 out) ----------
__global__ __launch_bounds__(256) void out_gemm(const u16* __restrict__ attn,
                                                const u16* __restrict__ Wob,
                                                const float* __restrict__ bo,
                                                float* __restrict__ out) {
  __shared__ char lds[16384];
  const int row0 = blockIdx.y * 128, col0 = blockIdx.x * 128;
  f32x4 acc[4][4];
  gemm_tile(attn, Wob, row0, col0, lds, lds + 8192, acc);

  const int tid = threadIdx.x;
  const int lane = tid & 63, wid = tid >> 6;
  const int wr = wid >> 1, wc = wid & 1;
  const int lg = lane >> 4, lr = lane & 15;
#pragma unroll
  for (int m = 0; m < 4; ++m)
#pragma unroll
    for (int n = 0; n < 4; ++n) {
      int col = col0 + wc * 64 + n * 16 + lr;
      float b = bo[col];
#pragma unroll
      for (int r = 0; r < 4; ++r) {
        int row = row0 + wr * 64 + m * 16 + lg * 4 + r;
        out[(size_t)row * DM + col] = acc[m][n][r] + b;
      }
    }
}

extern "C" void kernel_launch(void* const* d_in, const int* in_sizes, int n_in,
                              void* d_out, int out_size, void* d_ws, size_t ws_size,
                              hipStream_t stream) {
  const float* x = (const float*)d_in[0];
  const float* Wq = (const float*)d_in[1];
  const float* bq = (const float*)d_in[2];
  const float* Wk = (const float*)d_in[3];
  const float* bk = (const float*)d_in[4];
  const float* Wv = (const float*)d_in[5];
  const float* bv = (const float*)d_in[6];
  const float* Wo = (const float*)d_in[7];
  const float* bo = (const float*)d_in[8];

  char* ws = (char*)d_ws;
  const size_t MB = 1024 * 1024;
  u16* xb = (u16*)(ws);             // 8 MB (x bf16; reused as attn out later)
  u16* Wqb = (u16*)(ws + 8 * MB);   // 2 MB
  u16* Wkb = (u16*)(ws + 10 * MB);  // 2 MB
  u16* Wvb = (u16*)(ws + 12 * MB);  // 2 MB
  u16* Wob = (u16*)(ws + 14 * MB);  // 2 MB
  u16* Qb = (u16*)(ws + 16 * MB);   // 8 MB
  u16* Kb = (u16*)(ws + 24 * MB);   // 8 MB
  u16* VT = (u16*)(ws + 32 * MB);   // 8 MB   (total 40 MB)
  u16* attnb = xb;                  // alias: xb dead after qkv_gemm

  cvt_kernel<<<4096, 256, 0, stream>>>(x, xb, MROWS * DM, 1.0f);
  // Wq carries 1/sqrt(Dh) * log2(e)
  cvt4_kernel<<<dim3(1024, 4), 256, 0, stream>>>(Wq, Wk, Wv, Wo, Wqb, Wkb, Wvb,
                                                 Wob, 0.18033688011112042f);

  qkv_gemm<<<dim3(24, 32), 256, 0, stream>>>(xb, Wqb, Wkb, Wvb, bq, bk, bv, Qb, Kb, VT);
  attn_kernel<<<dim3(32, 32), 256, 0, stream>>>(Qb, Kb, VT, attnb);
  out_gemm<<<dim3(8, 32), 256, 0, stream>>>(attnb, Wob, bo, (float*)d_out);
}

// Round 6
// 113.547 us; speedup vs baseline: 1.9465x; 1.4070x over previous
//
#include <hip/hip_runtime.h>

// ---------- types ----------
typedef unsigned short u16;
typedef __bf16 bf16x8 __attribute__((ext_vector_type(8)));
typedef float f32x4 __attribute__((ext_vector_type(4)));
typedef float f32x16 __attribute__((ext_vector_type(16)));
typedef u16 u16x4 __attribute__((ext_vector_type(4)));
typedef unsigned int uint;

// B=2, T=2048, DM=1024, H=16, DH=64, M = B*T = 4096
#define DM 1024
#define MROWS 4096
#define TSEQ 2048

static __device__ __forceinline__ u16 f2b(float f) {
  uint u = __builtin_bit_cast(uint, f);
  uint r = (u + 0x7fffu + ((u >> 16) & 1u)) >> 16;  // RTN-even
  return (u16)r;
}

static __device__ __forceinline__ uint pkbf(float a, float b) {
  union { __bf16 h[2]; uint u; } x;
  x.h[0] = (__bf16)a; x.h[1] = (__bf16)b;
  return x.u;
}

// ---------- f32 -> bf16 conversion (optionally scaled) ----------
__global__ __launch_bounds__(256) void cvt_kernel(const float* __restrict__ in,
                                                  u16* __restrict__ out, int n,
                                                  float scale) {
  int i = (blockIdx.x * 256 + threadIdx.x) * 4;
  if (i >= n) return;
  float4 v = *(const float4*)(in + i);
  u16x4 o;
  o.x = f2b(v.x * scale); o.y = f2b(v.y * scale);
  o.z = f2b(v.z * scale); o.w = f2b(v.w * scale);
  *(u16x4*)(out + i) = o;
}

// batched 4-weight conversion (one launch instead of four)
__global__ __launch_bounds__(256) void cvt4_kernel(
    const float* __restrict__ w0, const float* __restrict__ w1,
    const float* __restrict__ w2, const float* __restrict__ w3,
    u16* __restrict__ o0, u16* __restrict__ o1, u16* __restrict__ o2,
    u16* __restrict__ o3, float s0) {
  const int sel = blockIdx.y;
  const float* in = (sel == 0) ? w0 : (sel == 1) ? w1 : (sel == 2) ? w2 : w3;
  u16* out = (sel == 0) ? o0 : (sel == 1) ? o1 : (sel == 2) ? o2 : o3;
  const float scale = (sel == 0) ? s0 : 1.0f;
  int i = (blockIdx.x * 256 + threadIdx.x) * 4;
  float4 v = *(const float4*)(in + i);
  u16x4 o;
  o.x = f2b(v.x * scale); o.y = f2b(v.y * scale);
  o.z = f2b(v.z * scale); o.w = f2b(v.w * scale);
  *(u16x4*)(out + i) = o;
}

// ---------- GEMM core: C[128x128] = A[128xK] * W[128xK]^T, K=1024 ----------
#define SWZ(o) ((o) ^ ((((o) >> 7) & 3) << 4))

static __device__ __forceinline__ void gemm_tile(const u16* __restrict__ A,
                                                 const u16* __restrict__ W,
                                                 int row0, int col0,
                                                 char* ldsA, char* ldsB,
                                                 f32x4 (&acc)[4][4]) {
  const int tid = threadIdx.x;
  const int lane = tid & 63, wid = tid >> 6;
  const int wr = wid >> 1, wc = wid & 1;
  const int lg = lane >> 4, lr = lane & 15;

  f32x4 z = {0.f, 0.f, 0.f, 0.f};
#pragma unroll
  for (int m = 0; m < 4; ++m)
#pragma unroll
    for (int n = 0; n < 4; ++n) acc[m][n] = z;

  for (int k0 = 0; k0 < DM; k0 += 32) {
#pragma unroll
    for (int c = 0; c < 2; ++c) {
      int lin = (c * 256 + tid) * 16;
      int p = SWZ(lin);
      int rowl = p >> 6;
      int cb = p & 63;
      const char* ga = (const char*)(A + (size_t)(row0 + rowl) * DM + k0) + cb;
      __builtin_amdgcn_global_load_lds(
          (const __attribute__((address_space(1))) void*)ga,
          (__attribute__((address_space(3))) void*)(ldsA + lin), 16, 0, 0);
      const char* gb = (const char*)(W + (size_t)(col0 + rowl) * DM + k0) + cb;
      __builtin_amdgcn_global_load_lds(
          (const __attribute__((address_space(1))) void*)gb,
          (__attribute__((address_space(3))) void*)(ldsB + lin), 16, 0, 0);
    }
    __syncthreads();

    bf16x8 av[4], bv[4];
#pragma unroll
    for (int m = 0; m < 4; ++m) {
      int bo = (wr * 64 + m * 16 + lr) * 64 + lg * 16;
      av[m] = *(const bf16x8*)(ldsA + SWZ(bo));
    }
#pragma unroll
    for (int n = 0; n < 4; ++n) {
      int bo = (wc * 64 + n * 16 + lr) * 64 + lg * 16;
      bv[n] = *(const bf16x8*)(ldsB + SWZ(bo));
    }
#pragma unroll
    for (int m = 0; m < 4; ++m)
#pragma unroll
      for (int n = 0; n < 4; ++n)
        acc[m][n] = __builtin_amdgcn_mfma_f32_16x16x32_bf16(av[m], bv[n], acc[m][n], 0, 0, 0);
    __syncthreads();
  }
}

// ---------- fused QKV projection ----------
// Q/K written in MFMA-fragment order: Q'[bh][tw][c][hi][ln][j] =
//   Q[t = tw*32+ln][dh = c*16+hi*8+j]   (2048 u16 per (bh,tw) tile)
// V written in P-fragment kv-permuted order: V'[bh][kt][c][hh][hi][ln][j] =
//   V[t : kvi = 16c + (j&3) + 8*(j>>2) + 4*hi][d = hh*32+ln]
// -> every attention global load is a contiguous, coalesced 1KB wave load.
__global__ __launch_bounds__(256) void qkv_gemm(
    const u16* __restrict__ xb, const u16* __restrict__ Wqb,
    const u16* __restrict__ Wkb, const u16* __restrict__ Wvb,
    const float* __restrict__ bq, const float* __restrict__ bk,
    const float* __restrict__ bv, u16* __restrict__ Qx, u16* __restrict__ Kx,
    u16* __restrict__ Vx) {
  __shared__ char lds[16384];
  const int seg = blockIdx.x >> 3, nt = blockIdx.x & 7;
  const int row0 = blockIdx.y * 128, col0 = nt * 128;
  const u16* W = (seg == 0) ? Wqb : (seg == 1) ? Wkb : Wvb;
  const float* bias = (seg == 0) ? bq : (seg == 1) ? bk : bv;
  // Q carries 1/sqrt(64) * log2(e) so attention works in exp2 domain
  const float bscale = (seg == 0) ? 0.18033688011112042f : 1.0f;

  f32x4 acc[4][4];
  gemm_tile(xb, W, row0, col0, lds, lds + 8192, acc);

  const int tid = threadIdx.x;
  const int lane = tid & 63, wid = tid >> 6;
  const int wr = wid >> 1, wc = wid & 1;
  const int lg = lane >> 4, lr = lane & 15;

  if (seg < 2) {
    u16* out = (seg == 0) ? Qx : Kx;
#pragma unroll
    for (int m = 0; m < 4; ++m)
#pragma unroll
      for (int n = 0; n < 4; ++n) {
        int col = col0 + wc * 64 + n * 16 + lr;
        float b = bias[col] * bscale;
        int h = col >> 6, dh = col & 63;
        int c = dh >> 4, hi2 = (dh >> 3) & 1, j = dh & 7;
#pragma unroll
        for (int r = 0; r < 4; ++r) {
          int row = row0 + wr * 64 + m * 16 + lg * 4 + r;
          int bI = row >> 11, tt = row & 2047;
          int tw = tt >> 5, ln2 = tt & 31;
          size_t idx =
              ((((((size_t)(bI * 16 + h) * 64 + tw) * 4 + c) * 2 + hi2) * 32) +
               ln2) * 8 + j;
          out[idx] = f2b(acc[m][n][r] + b);
        }
      }
  } else {
#pragma unroll
    for (int m = 0; m < 4; ++m)
#pragma unroll
      for (int n = 0; n < 4; ++n) {
        int col = col0 + wc * 64 + n * 16 + lr;
        float b = bias[col];
        int h = col >> 6, d = col & 63;
        int hh = d >> 5, ln2 = d & 31;
        int t = row0 + wr * 64 + m * 16 + lg * 4;
        int bI = t >> 11, tt = t & 2047;
        int kt = tt >> 5, kvi = tt & 31;
        int c = kvi >> 4, rem = kvi & 15;
        int hi2 = (rem >> 2) & 1, jh = (rem >> 3) & 1;  // j = r + 4*jh
        u16x4 pk;
        pk.x = f2b(acc[m][n][0] + b);
        pk.y = f2b(acc[m][n][1] + b);
        pk.z = f2b(acc[m][n][2] + b);
        pk.w = f2b(acc[m][n][3] + b);
        size_t idx =
            (((((((size_t)(bI * 16 + h) * 64 + kt) * 2 + c) * 2 + hh) * 2 +
               hi2) * 32) + ln2) * 8 + jh * 4;
        *(u16x4*)(Vx + idx) = pk;
      }
  }
}

// ---------- flash attention (causal), kv-split x2 + in-LDS merge ----------
// Block = one 64-row q-tile: 4 waves = {2 row-halves} x {2 kv-splits}.
// All global loads are contiguous 1KB wave loads (fragment-order Q'/K'/V').
// LPT: big q-tiles first per XCD; 4 heads/XCD keeps K'/V' L2-resident.
__global__ __launch_bounds__(256, 4) void attn_kernel(const u16* __restrict__ Qx,
                                                      const u16* __restrict__ Kx,
                                                      const u16* __restrict__ Vx,
                                                      u16* __restrict__ Aout) {
  __shared__ float mrg[2][64][32];  // per row-half merge buf, XOR-chunk swizzle
  __shared__ float mml[2][32][2];   // (m,l) per row
  const int tid = threadIdx.x, lane = tid & 63, wid = tid >> 6;
  const int hi = lane >> 5, ln = lane & 31;
  const int id = blockIdx.x + (blockIdx.y << 5);
  const int xcd = id & 7, idx = id >> 3;
  const int bh = xcd * 4 + (idx & 3);   // 4 heads per XCD
  const int qt = 31 - (idx >> 2);       // LPT: big q-tiles first
  const int b = bh >> 4, h = bh & 15;
  const int q0 = qt * 64 + (wid & 1) * 32;
  const int spl = wid >> 1;             // kv split id
  const int ntile = (q0 >> 5) + 1;
  const int half = (ntile + 1) >> 1;
  const int tbeg = spl ? half : 0;
  const int tend = spl ? ntile : half;

  const u16* Qp = Qx + ((size_t)bh * 64 + (q0 >> 5)) * 2048;
  const u16* Kbb = Kx + (size_t)bh * 64 * 2048;
  const u16* Vbb = Vx + (size_t)bh * 64 * 2048;

  bf16x8 qf[4];
#pragma unroll
  for (int c = 0; c < 4; ++c)
    qf[c] = *(const bf16x8*)(Qp + c * 512 + hi * 256 + ln * 8);

  f32x16 Oa, Ob;
#pragma unroll
  for (int r = 0; r < 16; ++r) { Oa[r] = 0.f; Ob[r] = 0.f; }
  float m = -1e30f, l = 0.f;

  bf16x8 kf[4], vf[4];
  auto loadK = [&](int kt) {
    const u16* Kp = Kbb + (size_t)kt * 2048;
#pragma unroll
    for (int c = 0; c < 4; ++c)
      kf[c] = *(const bf16x8*)(Kp + c * 512 + hi * 256 + ln * 8);
  };
  auto loadV = [&](int kt) {
    const u16* Vp = Vbb + (size_t)kt * 2048;
#pragma unroll
    for (int c = 0; c < 2; ++c)
#pragma unroll
      for (int hh = 0; hh < 2; ++hh)
        vf[2 * c + hh] =
            *(const bf16x8*)(Vp + (c * 2 + hh) * 512 + hi * 256 + ln * 8);
  };

  if (tbeg < tend) loadK(tbeg);
  for (int kt = tbeg; kt < tend; ++kt) {
    const int k0 = kt * 32;
    const bool diag = (kt == ntile - 1);
    loadV(kt);  // issued now, consumed after softmax -> latency hidden
    f32x16 S;
#pragma unroll
    for (int r = 0; r < 16; ++r) S[r] = 0.f;
    __builtin_amdgcn_s_setprio(1);
#pragma unroll
    for (int c = 0; c < 4; ++c)
      S = __builtin_amdgcn_mfma_f32_32x32x16_bf16(kf[c], qf[c], S, 0, 0, 0);
    __builtin_amdgcn_s_setprio(0);
    if (kt + 1 < tend) loadK(kt + 1);  // next K in flight under softmax+PV
    if (diag) {
      const int q = q0 + ln;
#pragma unroll
      for (int r = 0; r < 16; ++r) {
        int kv = k0 + (r & 3) + 8 * (r >> 2) + 4 * hi;
        if (kv > q) S[r] = -1e30f;
      }
    }
    float m0 = fmaxf(fmaxf(S[0], S[1]), fmaxf(S[2], S[3]));
    float m1 = fmaxf(fmaxf(S[4], S[5]), fmaxf(S[6], S[7]));
    float m2 = fmaxf(fmaxf(S[8], S[9]), fmaxf(S[10], S[11]));
    float m3 = fmaxf(fmaxf(S[12], S[13]), fmaxf(S[14], S[15]));
    float mx = fmaxf(fmaxf(m0, m1), fmaxf(m2, m3));
    mx = fmaxf(mx, __shfl_xor(mx, 32));
    if (!__all(mx - m <= 8.f)) {  // defer-max (T13), exp2 domain
      float nm = fmaxf(m, mx);
      float sf = __builtin_amdgcn_exp2f(m - nm);
      m = nm; l *= sf;
#pragma unroll
      for (int r = 0; r < 16; ++r) { Oa[r] *= sf; Ob[r] *= sf; }
    }
#pragma unroll
    for (int r = 0; r < 16; ++r) S[r] = __builtin_amdgcn_exp2f(S[r] - m);
    float ts = ((S[0] + S[1]) + (S[2] + S[3])) + ((S[4] + S[5]) + (S[6] + S[7]));
    ts += ((S[8] + S[9]) + (S[10] + S[11])) + ((S[12] + S[13]) + (S[14] + S[15]));
    ts += __shfl_xor(ts, 32);
    l += ts;
    uint pw[8];
#pragma unroll
    for (int i = 0; i < 8; ++i) pw[i] = pkbf(S[2 * i], S[2 * i + 1]);
    __builtin_amdgcn_s_setprio(1);
#pragma unroll
    for (int c = 0; c < 2; ++c) {
      union { uint w[4]; bf16x8 v; } pf;
      pf.w[0] = pw[4 * c + 0]; pf.w[1] = pw[4 * c + 1];
      pf.w[2] = pw[4 * c + 2]; pf.w[3] = pw[4 * c + 3];
      Oa = __builtin_amdgcn_mfma_f32_32x32x16_bf16(vf[2 * c + 0], pf.v, Oa, 0, 0, 0);
      Ob = __builtin_amdgcn_mfma_f32_32x32x16_bf16(vf[2 * c + 1], pf.v, Ob, 0, 0, 0);
    }
    __builtin_amdgcn_s_setprio(0);
  }

  // ---- kv-split merge via LDS ----
  union uo { f32x16 v; f32x4 q[4]; };
  const int pi = wid & 1;
  char* moc = (char*)&mrg[pi][0][0];
  const int sw8 = lane & 7;
  if (spl) {
    uo ua, ub; ua.v = Oa; ub.v = Ob;
#pragma unroll
    for (int c = 0; c < 4; ++c) {
      *(f32x4*)(moc + lane * 128 + ((c ^ sw8) * 16)) = ua.q[c];
      *(f32x4*)(moc + lane * 128 + (((c + 4) ^ sw8) * 16)) = ub.q[c];
    }
    if (hi == 0) { mml[pi][ln][0] = m; mml[pi][ln][1] = l; }
  }
  __syncthreads();
  if (spl) return;

  f32x4 rb[8];
#pragma unroll
  for (int c = 0; c < 8; ++c)
    rb[c] = *(const f32x4*)(moc + lane * 128 + ((c ^ sw8) * 16));
  float mB = mml[pi][ln][0], lB = mml[pi][ln][1];
  float M = fmaxf(m, mB);
  float eA = __builtin_amdgcn_exp2f(m - M);
  float eB = __builtin_amdgcn_exp2f(mB - M);
  float inv = 1.f / (l * eA + lB * eB);
  eA *= inv; eB *= inv;
  uo ua, ub; ua.v = Oa; ub.v = Ob;
#pragma unroll
  for (int c = 0; c < 4; ++c) {
    ua.q[c] = ua.q[c] * eA + rb[c] * eB;
    ub.q[c] = ub.q[c] * eA + rb[c + 4] * eB;
  }
  Oa = ua.v; Ob = ub.v;

  // epilogue: transpose O^T via LDS (reuse merge region), coalesced store
  char* Tc = moc;
#pragma unroll
  for (int i = 0; i < 8; ++i) {
    int d0 = (2 * i & 3) + 8 * ((2 * i) >> 2) + 4 * hi;
    uint wA = pkbf(Oa[2 * i], Oa[2 * i + 1]);
    *(uint*)(Tc + (ln * 128 + ((d0 * 2) ^ ((ln & 7) << 4)))) = wA;
    uint wB = pkbf(Ob[2 * i], Ob[2 * i + 1]);
    *(uint*)(Tc + (ln * 128 + (((d0 + 32) * 2) ^ ((ln & 7) << 4)))) = wB;
  }
  __threadfence_block();
  u16* Ap = Aout + (size_t)b * TSEQ * DM + h * 64 + (size_t)(q0 + ln) * DM;
#pragma unroll
  for (int j = 0; j < 4; ++j) {
    int oct = hi * 4 + j;
    bf16x8 v = *(const bf16x8*)(Tc + (ln * 128 + ((oct * 16) ^ ((ln & 7) << 4))));
    *(bf16x8*)(Ap + oct * 8) = v;
  }
}

// ---------- output projection: out = attn @ Wo^T + bo (f32 out) ----------
__global__ __launch_bounds__(256) void out_gemm(const u16* __restrict__ attn,
                                                const u16* __restrict__ Wob,
                                                const float* __restrict__ bo,
                                                float* __restrict__ out) {
  __shared__ char lds[16384];
  const int row0 = blockIdx.y * 128, col0 = blockIdx.x * 128;
  f32x4 acc[4][4];
  gemm_tile(attn, Wob, row0, col0, lds, lds + 8192, acc);

  const int tid = threadIdx.x;
  const int lane = tid & 63, wid = tid >> 6;
  const int wr = wid >> 1, wc = wid & 1;
  const int lg = lane >> 4, lr = lane & 15;
#pragma unroll
  for (int m = 0; m < 4; ++m)
#pragma unroll
    for (int n = 0; n < 4; ++n) {
      int col = col0 + wc * 64 + n * 16 + lr;
      float b = bo[col];
#pragma unroll
      for (int r = 0; r < 4; ++r) {
        int row = row0 + wr * 64 + m * 16 + lg * 4 + r;
        out[(size_t)row * DM + col] = acc[m][n][r] + b;
      }
    }
}

extern "C" void kernel_launch(void* const* d_in, const int* in_sizes, int n_in,
                              void* d_out, int out_size, void* d_ws, size_t ws_size,
                              hipStream_t stream) {
  const float* x = (const float*)d_in[0];
  const float* Wq = (const float*)d_in[1];
  const float* bq = (const float*)d_in[2];
  const float* Wk = (const float*)d_in[3];
  const float* bk = (const float*)d_in[4];
  const float* Wv = (const float*)d_in[5];
  const float* bv = (const float*)d_in[6];
  const float* Wo = (const float*)d_in[7];
  const float* bo = (const float*)d_in[8];

  char* ws = (char*)d_ws;
  const size_t MB = 1024 * 1024;
  u16* xb = (u16*)(ws);             // 8 MB (x bf16; reused as attn out later)
  u16* Wqb = (u16*)(ws + 8 * MB);   // 2 MB
  u16* Wkb = (u16*)(ws + 10 * MB);  // 2 MB
  u16* Wvb = (u16*)(ws + 12 * MB);  // 2 MB
  u16* Wob = (u16*)(ws + 14 * MB);  // 2 MB
  u16* Qf = (u16*)(ws + 16 * MB);   // 8 MB (fragment-order Q')
  u16* Kf = (u16*)(ws + 24 * MB);   // 8 MB (fragment-order K')
  u16* Vf = (u16*)(ws + 32 * MB);   // 8 MB (fragment-order V')  total 40 MB
  u16* attnb = xb;                  // alias: xb dead after qkv_gemm

  cvt_kernel<<<4096, 256, 0, stream>>>(x, xb, MROWS * DM, 1.0f);
  // Wq carries 1/sqrt(Dh) * log2(e)
  cvt4_kernel<<<dim3(1024, 4), 256, 0, stream>>>(Wq, Wk, Wv, Wo, Wqb, Wkb, Wvb,
                                                 Wob, 0.18033688011112042f);

  qkv_gemm<<<dim3(24, 32), 256, 0, stream>>>(xb, Wqb, Wkb, Wvb, bq, bk, bv, Qf, Kf, Vf);
  attn_kernel<<<dim3(32, 32), 256, 0, stream>>>(Qf, Kf, Vf, attnb);
  out_gemm<<<dim3(8, 32), 256, 0, stream>>>(attnb, Wob, bo, (float*)d_out);
}

// Round 7
// 96.003 us; speedup vs baseline: 2.3022x; 1.1827x over previous
//
#include <hip/hip_runtime.h>

// ---------- types ----------
typedef unsigned short u16;
typedef __bf16 bf16x8 __attribute__((ext_vector_type(8)));
typedef float f32x4 __attribute__((ext_vector_type(4)));
typedef float f32x16 __attribute__((ext_vector_type(16)));
typedef u16 u16x4 __attribute__((ext_vector_type(4)));
typedef unsigned int uint;

// B=2, T=2048, DM=1024, H=16, DH=64, M = B*T = 4096
#define DM 1024
#define MROWS 4096
#define TSEQ 2048

static __device__ __forceinline__ u16 f2b(float f) {
  uint u = __builtin_bit_cast(uint, f);
  uint r = (u + 0x7fffu + ((u >> 16) & 1u)) >> 16;  // RTN-even
  return (u16)r;
}

static __device__ __forceinline__ uint pkbf(float a, float b) {
  union { __bf16 h[2]; uint u; } x;
  x.h[0] = (__bf16)a; x.h[1] = (__bf16)b;
  return x.u;
}

// ---------- f32 -> bf16 conversion (optionally scaled) ----------
__global__ __launch_bounds__(256) void cvt_kernel(const float* __restrict__ in,
                                                  u16* __restrict__ out, int n,
                                                  float scale) {
  int i = (blockIdx.x * 256 + threadIdx.x) * 4;
  if (i >= n) return;
  float4 v = *(const float4*)(in + i);
  u16x4 o;
  o.x = f2b(v.x * scale); o.y = f2b(v.y * scale);
  o.z = f2b(v.z * scale); o.w = f2b(v.w * scale);
  *(u16x4*)(out + i) = o;
}

// batched 4-weight conversion (one launch instead of four)
__global__ __launch_bounds__(256) void cvt4_kernel(
    const float* __restrict__ w0, const float* __restrict__ w1,
    const float* __restrict__ w2, const float* __restrict__ w3,
    u16* __restrict__ o0, u16* __restrict__ o1, u16* __restrict__ o2,
    u16* __restrict__ o3, float s0) {
  const int sel = blockIdx.y;
  const float* in = (sel == 0) ? w0 : (sel == 1) ? w1 : (sel == 2) ? w2 : w3;
  u16* out = (sel == 0) ? o0 : (sel == 1) ? o1 : (sel == 2) ? o2 : o3;
  const float scale = (sel == 0) ? s0 : 1.0f;
  int i = (blockIdx.x * 256 + threadIdx.x) * 4;
  float4 v = *(const float4*)(in + i);
  u16x4 o;
  o.x = f2b(v.x * scale); o.y = f2b(v.y * scale);
  o.z = f2b(v.z * scale); o.w = f2b(v.w * scale);
  *(u16x4*)(out + i) = o;
}

// ---------- GEMM core: C[128x128] = A[128xK] * W[128xK]^T, K=1024 ----------
// 2-phase double-buffered (T3 minimum): stage(next) issued BEFORE current
// compute; compiler's vmcnt(0)-before-barrier then lands after ~250cyc of
// ds_read+MFMA -> staging latency hidden. One barrier per K-step.
// LDS: buf0 A@0 B@8192, buf1 A@16384 B@24576 (32 KB).
#define SWZ(o) ((o) ^ ((((o) >> 7) & 3) << 4))

static __device__ __forceinline__ void gemm_tile(const u16* __restrict__ A,
                                                 const u16* __restrict__ W,
                                                 int row0, int col0,
                                                 char* lds,
                                                 f32x4 (&acc)[4][4]) {
  const int tid = threadIdx.x;
  const int lane = tid & 63, wid = tid >> 6;
  const int wr = wid >> 1, wc = wid & 1;
  const int lg = lane >> 4, lr = lane & 15;

  // loop-invariant staging sources (pre-swizzled) and LDS dests
  const u16* srcA[2]; const u16* srcB[2]; int dst[2];
#pragma unroll
  for (int c = 0; c < 2; ++c) {
    int lin = (c * 256 + tid) * 16;
    int p = SWZ(lin);
    srcA[c] = A + (size_t)(row0 + (p >> 6)) * DM + ((p & 63) >> 1);
    srcB[c] = W + (size_t)(col0 + (p >> 6)) * DM + ((p & 63) >> 1);
    dst[c] = lin;
  }
  // loop-invariant ds_read offsets
  int offA[4], offB[4];
#pragma unroll
  for (int m = 0; m < 4; ++m) offA[m] = SWZ((wr * 64 + m * 16 + lr) * 64 + lg * 16);
#pragma unroll
  for (int n = 0; n < 4; ++n) offB[n] = SWZ((wc * 64 + n * 16 + lr) * 64 + lg * 16);

  f32x4 z = {0.f, 0.f, 0.f, 0.f};
#pragma unroll
  for (int m = 0; m < 4; ++m)
#pragma unroll
    for (int n = 0; n < 4; ++n) acc[m][n] = z;

  auto stage = [&](int k0, int buf) {
    char* bA = lds + buf * 16384;
    char* bB = bA + 8192;
#pragma unroll
    for (int c = 0; c < 2; ++c) {
      __builtin_amdgcn_global_load_lds(
          (const __attribute__((address_space(1))) void*)(srcA[c] + k0),
          (__attribute__((address_space(3))) void*)(bA + dst[c]), 16, 0, 0);
      __builtin_amdgcn_global_load_lds(
          (const __attribute__((address_space(1))) void*)(srcB[c] + k0),
          (__attribute__((address_space(3))) void*)(bB + dst[c]), 16, 0, 0);
    }
  };

  stage(0, 0);
  __syncthreads();
  int cur = 0;
  for (int k0 = 0; k0 < DM; k0 += 32) {
    if (k0 + 32 < DM) stage(k0 + 32, cur ^ 1);  // prefetch under compute
    char* bA = lds + cur * 16384;
    char* bB = bA + 8192;
    bf16x8 av[4], bv[4];
#pragma unroll
    for (int m = 0; m < 4; ++m) av[m] = *(const bf16x8*)(bA + offA[m]);
#pragma unroll
    for (int n = 0; n < 4; ++n) bv[n] = *(const bf16x8*)(bB + offB[n]);
    __builtin_amdgcn_s_setprio(1);
#pragma unroll
    for (int m = 0; m < 4; ++m)
#pragma unroll
      for (int n = 0; n < 4; ++n)
        acc[m][n] = __builtin_amdgcn_mfma_f32_16x16x32_bf16(av[m], bv[n], acc[m][n], 0, 0, 0);
    __builtin_amdgcn_s_setprio(0);
    __syncthreads();  // drains vmcnt(0): prefetch complete; buf[cur] reusable
    cur ^= 1;
  }
}

// ---------- fused QKV projection ----------
// Q/K written in MFMA-fragment order: Q'[bh][tw][c][hi][ln][j] =
//   Q[t = tw*32+ln][dh = c*16+hi*8+j]   (2048 u16 per (bh,tw) tile)
// V written in P-fragment kv-permuted order: V'[bh][kt][c][hh][hi][ln][j] =
//   V[t : kvi = 16c + (j&3) + 8*(j>>2) + 4*hi][d = hh*32+ln]
// Epilogue: acc -> LDS bf16 tile (row-XOR swizzle) -> contiguous b128 stores.
__global__ __launch_bounds__(256) void qkv_gemm(
    const u16* __restrict__ xb, const u16* __restrict__ Wqb,
    const u16* __restrict__ Wkb, const u16* __restrict__ Wvb,
    const float* __restrict__ bq, const float* __restrict__ bk,
    const float* __restrict__ bv, u16* __restrict__ Qx, u16* __restrict__ Kx,
    u16* __restrict__ Vx) {
  __shared__ char lds[32768];
  const int seg = blockIdx.x >> 3, nt = blockIdx.x & 7;
  const int row0 = blockIdx.y * 128, col0 = nt * 128;
  const u16* W = (seg == 0) ? Wqb : (seg == 1) ? Wkb : Wvb;
  const float* bias = (seg == 0) ? bq : (seg == 1) ? bk : bv;
  // Q carries 1/sqrt(64) * log2(e) so attention works in exp2 domain
  const float bscale = (seg == 0) ? 0.18033688011112042f : 1.0f;

  f32x4 acc[4][4];
  gemm_tile(xb, W, row0, col0, lds, acc);

  const int tid = threadIdx.x;
  const int lane = tid & 63, wid = tid >> 6;
  const int wr = wid >> 1, wc = wid & 1;
  const int lg = lane >> 4, lr = lane & 15;

  // ---- stage output tile to LDS: bf16 [row 0..127][col 0..127],
  //      byte = row*256 + ((col*2) ^ ((row&7)<<4))  (16B-granule swizzle)
  float bcol[4];
#pragma unroll
  for (int n = 0; n < 4; ++n) bcol[n] = bias[col0 + wc * 64 + n * 16 + lr] * bscale;
#pragma unroll
  for (int m = 0; m < 4; ++m)
#pragma unroll
    for (int n = 0; n < 4; ++n) {
      int colB = (wc * 64 + n * 16 + lr) * 2;
#pragma unroll
      for (int r = 0; r < 4; ++r) {
        int row = wr * 64 + m * 16 + lg * 4 + r;
        *(u16*)(lds + row * 256 + (colB ^ ((row & 7) << 4))) =
            f2b(acc[m][n][r] + bcol[n]);
      }
    }
  __syncthreads();

  const int st = tid >> 5, lnq = tid & 31;
  const int bI = row0 >> 11;
  if (seg < 2) {
    u16* out = (seg == 0) ? Qx : Kx;
    const int hloc = st & 1, twloc = st >> 1;
    const int h = (col0 >> 6) + hloc;
    const int tw = ((row0 & 2047) >> 5) + twloc;
    u16* base = out + ((size_t)(bI * 16 + h) * 64 + tw) * 2048;
#pragma unroll
    for (int ch = 0; ch < 8; ++ch) {
      int q = ch * 256 + lnq * 8;
      int c = q >> 9, hi2 = (q >> 8) & 1;
      int row = twloc * 32 + lnq;
      int colB = hloc * 128 + c * 32 + hi2 * 16;
      bf16x8 v = *(const bf16x8*)(lds + row * 256 + (colB ^ ((row & 7) << 4)));
      *(bf16x8*)(base + q) = v;
    }
  } else {
    const int hloc = st & 1, ktloc = st >> 1;
    const int h = (col0 >> 6) + hloc;
    const int kt = ((row0 & 2047) >> 5) + ktloc;
    u16* base = Vx + ((size_t)(bI * 16 + h) * 64 + kt) * 2048;
#pragma unroll
    for (int ch = 0; ch < 8; ++ch) {
      int q = ch * 256 + lnq * 8;
      int hi2 = ch & 1, hh = (ch >> 1) & 1, c = (ch >> 2) & 1;
      int colB = (hloc * 64 + hh * 32 + lnq) * 2;
      union { u16 a[8]; bf16x8 v; } t;
#pragma unroll
      for (int j = 0; j < 8; ++j) {
        int kvi = 16 * c + (j & 3) + 8 * (j >> 2) + 4 * hi2;
        int row = ktloc * 32 + kvi;
        t.a[j] = *(const u16*)(lds + row * 256 + (colB ^ ((row & 7) << 4)));
      }
      *(bf16x8*)(base + q) = t.v;
    }
  }
}

// ---------- flash attention (causal), kv-split x2 + in-LDS merge ----------
// Block = one 64-row q-tile: 4 waves = {2 row-halves} x {2 kv-splits}.
// All global loads are contiguous 1KB wave loads (fragment-order Q'/K'/V').
// LPT: big q-tiles first per XCD; 4 heads/XCD keeps K'/V' L2-resident.
__global__ __launch_bounds__(256, 4) void attn_kernel(const u16* __restrict__ Qx,
                                                      const u16* __restrict__ Kx,
                                                      const u16* __restrict__ Vx,
                                                      u16* __restrict__ Aout) {
  __shared__ float mrg[2][64][32];  // per row-half merge buf, XOR-chunk swizzle
  __shared__ float mml[2][32][2];   // (m,l) per row
  const int tid = threadIdx.x, lane = tid & 63, wid = tid >> 6;
  const int hi = lane >> 5, ln = lane & 31;
  const int id = blockIdx.x + (blockIdx.y << 5);
  const int xcd = id & 7, idx = id >> 3;
  const int bh = xcd * 4 + (idx & 3);   // 4 heads per XCD
  const int qt = 31 - (idx >> 2);       // LPT: big q-tiles first
  const int b = bh >> 4, h = bh & 15;
  const int q0 = qt * 64 + (wid & 1) * 32;
  const int spl = wid >> 1;             // kv split id
  const int ntile = (q0 >> 5) + 1;
  const int half = (ntile + 1) >> 1;
  const int tbeg = spl ? half : 0;
  const int tend = spl ? ntile : half;

  const u16* Qp = Qx + ((size_t)bh * 64 + (q0 >> 5)) * 2048;
  const u16* Kbb = Kx + (size_t)bh * 64 * 2048;
  const u16* Vbb = Vx + (size_t)bh * 64 * 2048;

  bf16x8 qf[4];
#pragma unroll
  for (int c = 0; c < 4; ++c)
    qf[c] = *(const bf16x8*)(Qp + c * 512 + hi * 256 + ln * 8);

  f32x16 Oa, Ob;
#pragma unroll
  for (int r = 0; r < 16; ++r) { Oa[r] = 0.f; Ob[r] = 0.f; }
  float m = -1e30f, l = 0.f;

  bf16x8 kf[4], vf[4];
  auto loadK = [&](int kt) {
    const u16* Kp = Kbb + (size_t)kt * 2048;
#pragma unroll
    for (int c = 0; c < 4; ++c)
      kf[c] = *(const bf16x8*)(Kp + c * 512 + hi * 256 + ln * 8);
  };
  auto loadV = [&](int kt) {
    const u16* Vp = Vbb + (size_t)kt * 2048;
#pragma unroll
    for (int c = 0; c < 2; ++c)
#pragma unroll
      for (int hh = 0; hh < 2; ++hh)
        vf[2 * c + hh] =
            *(const bf16x8*)(Vp + (c * 2 + hh) * 512 + hi * 256 + ln * 8);
  };

  if (tbeg < tend) loadK(tbeg);
  for (int kt = tbeg; kt < tend; ++kt) {
    const int k0 = kt * 32;
    const bool diag = (kt == ntile - 1);
    loadV(kt);  // issued now, consumed after softmax -> latency hidden
    f32x16 S;
#pragma unroll
    for (int r = 0; r < 16; ++r) S[r] = 0.f;
    __builtin_amdgcn_s_setprio(1);
#pragma unroll
    for (int c = 0; c < 4; ++c)
      S = __builtin_amdgcn_mfma_f32_32x32x16_bf16(kf[c], qf[c], S, 0, 0, 0);
    __builtin_amdgcn_s_setprio(0);
    if (kt + 1 < tend) loadK(kt + 1);  // next K in flight under softmax+PV
    if (diag) {
      const int q = q0 + ln;
#pragma unroll
      for (int r = 0; r < 16; ++r) {
        int kv = k0 + (r & 3) + 8 * (r >> 2) + 4 * hi;
        if (kv > q) S[r] = -1e30f;
      }
    }
    float m0 = fmaxf(fmaxf(S[0], S[1]), fmaxf(S[2], S[3]));
    float m1 = fmaxf(fmaxf(S[4], S[5]), fmaxf(S[6], S[7]));
    float m2 = fmaxf(fmaxf(S[8], S[9]), fmaxf(S[10], S[11]));
    float m3 = fmaxf(fmaxf(S[12], S[13]), fmaxf(S[14], S[15]));
    float mx = fmaxf(fmaxf(m0, m1), fmaxf(m2, m3));
    mx = fmaxf(mx, __shfl_xor(mx, 32));
    if (!__all(mx - m <= 8.f)) {  // defer-max (T13), exp2 domain
      float nm = fmaxf(m, mx);
      float sf = __builtin_amdgcn_exp2f(m - nm);
      m = nm; l *= sf;
#pragma unroll
      for (int r = 0; r < 16; ++r) { Oa[r] *= sf; Ob[r] *= sf; }
    }
#pragma unroll
    for (int r = 0; r < 16; ++r) S[r] = __builtin_amdgcn_exp2f(S[r] - m);
    float ts = ((S[0] + S[1]) + (S[2] + S[3])) + ((S[4] + S[5]) + (S[6] + S[7]));
    ts += ((S[8] + S[9]) + (S[10] + S[11])) + ((S[12] + S[13]) + (S[14] + S[15]));
    ts += __shfl_xor(ts, 32);
    l += ts;
    uint pw[8];
#pragma unroll
    for (int i = 0; i < 8; ++i) pw[i] = pkbf(S[2 * i], S[2 * i + 1]);
    __builtin_amdgcn_s_setprio(1);
#pragma unroll
    for (int c = 0; c < 2; ++c) {
      union { uint w[4]; bf16x8 v; } pf;
      pf.w[0] = pw[4 * c + 0]; pf.w[1] = pw[4 * c + 1];
      pf.w[2] = pw[4 * c + 2]; pf.w[3] = pw[4 * c + 3];
      Oa = __builtin_amdgcn_mfma_f32_32x32x16_bf16(vf[2 * c + 0], pf.v, Oa, 0, 0, 0);
      Ob = __builtin_amdgcn_mfma_f32_32x32x16_bf16(vf[2 * c + 1], pf.v, Ob, 0, 0, 0);
    }
    __builtin_amdgcn_s_setprio(0);
  }

  // ---- kv-split merge via LDS ----
  union uo { f32x16 v; f32x4 q[4]; };
  const int pi = wid & 1;
  char* moc = (char*)&mrg[pi][0][0];
  const int sw8 = lane & 7;
  if (spl) {
    uo ua, ub; ua.v = Oa; ub.v = Ob;
#pragma unroll
    for (int c = 0; c < 4; ++c) {
      *(f32x4*)(moc + lane * 128 + ((c ^ sw8) * 16)) = ua.q[c];
      *(f32x4*)(moc + lane * 128 + (((c + 4) ^ sw8) * 16)) = ub.q[c];
    }
    if (hi == 0) { mml[pi][ln][0] = m; mml[pi][ln][1] = l; }
  }
  __syncthreads();
  if (spl) return;

  f32x4 rb[8];
#pragma unroll
  for (int c = 0; c < 8; ++c)
    rb[c] = *(const f32x4*)(moc + lane * 128 + ((c ^ sw8) * 16));
  float mB = mml[pi][ln][0], lB = mml[pi][ln][1];
  float M = fmaxf(m, mB);
  float eA = __builtin_amdgcn_exp2f(m - M);
  float eB = __builtin_amdgcn_exp2f(mB - M);
  float inv = 1.f / (l * eA + lB * eB);
  eA *= inv; eB *= inv;
  uo ua, ub; ua.v = Oa; ub.v = Ob;
#pragma unroll
  for (int c = 0; c < 4; ++c) {
    ua.q[c] = ua.q[c] * eA + rb[c] * eB;
    ub.q[c] = ub.q[c] * eA + rb[c + 4] * eB;
  }
  Oa = ua.v; Ob = ub.v;

  // epilogue: transpose O^T via LDS (reuse merge region), coalesced store
  char* Tc = moc;
#pragma unroll
  for (int i = 0; i < 8; ++i) {
    int d0 = (2 * i & 3) + 8 * ((2 * i) >> 2) + 4 * hi;
    uint wA = pkbf(Oa[2 * i], Oa[2 * i + 1]);
    *(uint*)(Tc + (ln * 128 + ((d0 * 2) ^ ((ln & 7) << 4)))) = wA;
    uint wB = pkbf(Ob[2 * i], Ob[2 * i + 1]);
    *(uint*)(Tc + (ln * 128 + (((d0 + 32) * 2) ^ ((ln & 7) << 4)))) = wB;
  }
  __threadfence_block();
  u16* Ap = Aout + (size_t)b * TSEQ * DM + h * 64 + (size_t)(q0 + ln) * DM;
#pragma unroll
  for (int j = 0; j < 4; ++j) {
    int oct = hi * 4 + j;
    bf16x8 v = *(const bf16x8*)(Tc + (ln * 128 + ((oct * 16) ^ ((ln & 7) << 4))));
    *(bf16x8*)(Ap + oct * 8) = v;
  }
}

// ---------- output projection: out = attn @ Wo^T + bo (f32 out) ----------
__global__ __launch_bounds__(256) void out_gemm(const u16* __restrict__ attn,
                                                const u16* __restrict__ Wob,
                                                const float* __restrict__ bo,
                                                float* __restrict__ out) {
  __shared__ char lds[32768];
  const int row0 = blockIdx.y * 128, col0 = blockIdx.x * 128;
  f32x4 acc[4][4];
  gemm_tile(attn, Wob, row0, col0, lds, acc);

  const int tid = threadIdx.x;
  const int lane = tid & 63, wid = tid >> 6;
  const int wr = wid >> 1, wc = wid & 1;
  const int lg = lane >> 4, lr = lane & 15;
#pragma unroll
  for (int m = 0; m < 4; ++m)
#pragma unroll
    for (int n = 0; n < 4; ++n) {
      int col = col0 + wc * 64 + n * 16 + lr;
      float b = bo[col];
#pragma unroll
      for (int r = 0; r < 4; ++r) {
        int row = row0 + wr * 64 + m * 16 + lg * 4 + r;
        out[(size_t)row * DM + col] = acc[m][n][r] + b;
      }
    }
}

extern "C" void kernel_launch(void* const* d_in, const int* in_sizes, int n_in,
                              void* d_out, int out_size, void* d_ws, size_t ws_size,
                              hipStream_t stream) {
  const float* x = (const float*)d_in[0];
  const float* Wq = (const float*)d_in[1];
  const float* bq = (const float*)d_in[2];
  const float* Wk = (const float*)d_in[3];
  const float* bk = (const float*)d_in[4];
  const float* Wv = (const float*)d_in[5];
  const float* bv = (const float*)d_in[6];
  const float* Wo = (const float*)d_in[7];
  const float* bo = (const float*)d_in[8];

  char* ws = (char*)d_ws;
  const size_t MB = 1024 * 1024;
  u16* xb = (u16*)(ws);             // 8 MB (x bf16; reused as attn out later)
  u16* Wqb = (u16*)(ws + 8 * MB);   // 2 MB
  u16* Wkb = (u16*)(ws + 10 * MB);  // 2 MB
  u16* Wvb = (u16*)(ws + 12 * MB);  // 2 MB
  u16* Wob = (u16*)(ws + 14 * MB);  // 2 MB
  u16* Qf = (u16*)(ws + 16 * MB);   // 8 MB (fragment-order Q')
  u16* Kf = (u16*)(ws + 24 * MB);   // 8 MB (fragment-order K')
  u16* Vf = (u16*)(ws + 32 * MB);   // 8 MB (fragment-order V')  total 40 MB
  u16* attnb = xb;                  // alias: xb dead after qkv_gemm

  cvt_kernel<<<4096, 256, 0, stream>>>(x, xb, MROWS * DM, 1.0f);
  // Wq carries 1/sqrt(Dh) * log2(e)
  cvt4_kernel<<<dim3(1024, 4), 256, 0, stream>>>(Wq, Wk, Wv, Wo, Wqb, Wkb, Wvb,
                                                 Wob, 0.18033688011112042f);

  qkv_gemm<<<dim3(24, 32), 256, 0, stream>>>(xb, Wqb, Wkb, Wvb, bq, bk, bv, Qf, Kf, Vf);
  attn_kernel<<<dim3(32, 32), 256, 0, stream>>>(Qf, Kf, Vf, attnb);
  out_gemm<<<dim3(8, 32), 256, 0, stream>>>(attnb, Wob, bo, (float*)d_out);
}